// Round 12
// baseline (26.952 us; speedup 1.0000x reference)
//
#include <hip/hip_runtime.h>
#include <math.h>

// h [8,4096,512] f32, patch_ids [8,4096] i32 sorted per batch, P=1024, k=4.
// Out [8,1024,512] f32.
#define BS   8
#define SEQ  4096
#define DIM  512
#define NP   1024
#define KTOP 4
#define GRP  4                 // consecutive patches per block
#define NEGINF_C (-1.0e9f)

typedef float f32x4 __attribute__((ext_vector_type(4)));

// ---------------------------------------------------------------------------
// 9-op insertion into descending 5-list (multiset top-5); dup handling via
// once-per-patch epilogue dedup (exact: R9/R10/R11 absmax 0.0). Only genuine
// data ties enter (tail tokens are index-skipped, never clamp-duplicated).
// ---------------------------------------------------------------------------
__device__ __forceinline__ void ins5(float v, float& m0, float& m1, float& m2,
                                     float& m3, float& m4) {
    float a;
    a = fmaxf(m0, v); v = fminf(m0, v); m0 = a;
    a = fmaxf(m1, v); v = fminf(m1, v); m1 = a;
    a = fmaxf(m2, v); v = fminf(m2, v); m2 = a;
    a = fmaxf(m3, v); v = fminf(m3, v); m3 = a;
    m4 = fmaxf(m4, v);
}

__device__ __forceinline__ float dedup_avg(float s0, float s1, float s2, float s3,
                                           float s4, int n, float inv_n) {
    const bool e1 = (s1 == s0) & (s1 != -INFINITY);
    const bool e2 = (s2 == s1) & (s2 != -INFINITY);
    const bool e3 = (s3 == s2) & (s3 != -INFINITY);
    const float o1 = e1 ? s2 : s1;
    const float o2 = (e1 | e2) ? s3 : s2;
    const float o3 = (e1 | e2 | e3) ? s4 : s3;
    float acc = (s0 == -INFINITY) ? NEGINF_C : s0;          // n >= 1 here
    if (n > 1) acc += (o1 == -INFINITY) ? NEGINF_C : o1;
    if (n > 2) acc += (o2 == -INFINITY) ? NEGINF_C : o2;
    if (n > 3) acc += (o3 == -INFINITY) ? NEGINF_C : o3;
    return acc * inv_n;
}

// ---------------------------------------------------------------------------
// One block per (b, 4 consecutive patches): 2048 blocks x 128 thr (2 waves)
// = 4096 waves, fully co-resident. Streams the contiguous token range with
// a 1-deep chunk-4 load pipeline: next chunk's loads issue before current
// chunk's ins5. Patch flush on wave-uniform id change.
// ---------------------------------------------------------------------------
__global__ __launch_bounds__(128) void topk_stream_kernel(const float* __restrict__ h,
                                                          const int* __restrict__ pid,
                                                          float* __restrict__ out) {
    const int g   = blockIdx.x;
    const int b   = g >> 8;                 // / (NP/GRP)
    const int p0  = (g & 255) * GRP;
    const int tid = threadIdx.x;
    const int* ids = pid + b * SEQ;

    // lower_bound(ids, p0 + (lane&1)*GRP), 13 guarded steps
    const int target = p0 + (tid & 1) * GRP;
    int lo = 0, hi = SEQ;
    #pragma unroll
    for (int s = 0; s < 13; ++s) {
        const int mid  = (lo + hi) >> 1;
        const int midc = (mid < SEQ) ? mid : (SEQ - 1);
        const bool go  = (ids[midc] < target) & (mid < hi);
        lo = go ? mid + 1 : lo;
        hi = go ? hi : mid;
    }
    const int start = __shfl(lo, 0);
    const int end   = __shfl(lo, 1);

    f32x4* outb = (f32x4*)(out + ((size_t)b * NP + p0) * DIM);   // patch p0 row
    const f32x4 zv = (f32x4){0.f, 0.f, 0.f, 0.f};

    float a0 = -INFINITY, a1 = -INFINITY, a2 = -INFINITY, a3 = -INFINITY, a4 = -INFINITY;
    float b0 = -INFINITY, b1 = -INFINITY, b2 = -INFINITY, b3 = -INFINITY, b4 = -INFINITY;
    float c0 = -INFINITY, c1 = -INFINITY, c2 = -INFINITY, c3 = -INFINITY, c4 = -INFINITY;
    float d0 = -INFINITY, d1 = -INFINITY, d2 = -INFINITY, d3 = -INFINITY, d4 = -INFINITY;
    int cnt = 0;
    int cur = p0 - 1;                        // no active patch yet

#define RESET_ACC()                                                          \
    do {                                                                     \
        a0 = a1 = a2 = a3 = a4 = -INFINITY;                                  \
        b0 = b1 = b2 = b3 = b4 = -INFINITY;                                  \
        c0 = c1 = c2 = c3 = c4 = -INFINITY;                                  \
        d0 = d1 = d2 = d3 = d4 = -INFINITY;                                  \
    } while (0)

#define FLUSH(P)                                                             \
    do {                                                                     \
        const int   n_    = (cnt < KTOP) ? cnt : KTOP;                       \
        const float invn_ = 1.0f / (float)n_;                                \
        f32x4 r_;                                                            \
        r_.x = dedup_avg(a0, a1, a2, a3, a4, n_, invn_);                     \
        r_.y = dedup_avg(b0, b1, b2, b3, b4, n_, invn_);                     \
        r_.z = dedup_avg(c0, c1, c2, c3, c4, n_, invn_);                     \
        r_.w = dedup_avg(d0, d1, d2, d3, d4, n_, invn_);                     \
        __builtin_nontemporal_store(r_, &outb[(size_t)((P) - p0) * (DIM / 4) + tid]); \
    } while (0)

#define ZERO(P) __builtin_nontemporal_store(zv, &outb[(size_t)((P) - p0) * (DIM / 4) + tid])

    if (start < end) {
        const f32x4* hb  = (const f32x4*)(h + (size_t)b * SEQ * DIM);
        const int    lastrow = end - 1;

        // prefetch chunk 0
        f32x4 V[4]; int I[4];
        #pragma unroll
        for (int i = 0; i < 4; ++i) {
            const int tc = (start + i < end) ? start + i : lastrow;
            V[i] = hb[(size_t)tc * (DIM / 4) + tid];
            I[i] = ids[tc];
        }

        for (int t = start; t < end; t += 4) {
            // ---- issue next chunk's loads BEFORE consuming current ----
            f32x4 Vn[4]; int In[4];
            #pragma unroll
            for (int i = 0; i < 4; ++i) {
                const int tn = (t + 4 + i < end) ? t + 4 + i : lastrow;
                Vn[i] = hb[(size_t)tn * (DIM / 4) + tid];
                In[i] = ids[tn];
            }
            // ---- consume current chunk (index-skipped tail: exact work) ----
            #pragma unroll
            for (int i = 0; i < 4; ++i) {
                if (t + i < end) {                       // wave-uniform
                    const int id = I[i];
                    if (id != cur) {                     // wave-uniform
                        if (cur >= p0) FLUSH(cur);
                        for (int q = (cur < p0 ? p0 : cur + 1); q < id; ++q) ZERO(q);
                        cur = id; cnt = 0;
                        RESET_ACC();
                    }
                    ins5(V[i].x, a0, a1, a2, a3, a4);
                    ins5(V[i].y, b0, b1, b2, b3, b4);
                    ins5(V[i].z, c0, c1, c2, c3, c4);
                    ins5(V[i].w, d0, d1, d2, d3, d4);
                    ++cnt;
                }
            }
            #pragma unroll
            for (int i = 0; i < 4; ++i) { V[i] = Vn[i]; I[i] = In[i]; }
        }
        FLUSH(cur);                                      // start<end => cur>=p0
    }
    for (int q = (cur < p0 ? p0 : cur + 1); q < p0 + GRP; ++q) ZERO(q);

#undef RESET_ACC
#undef FLUSH
#undef ZERO
}

// ---------------------------------------------------------------------------
extern "C" void kernel_launch(void* const* d_in, const int* in_sizes, int n_in,
                              void* d_out, int out_size, void* d_ws, size_t ws_size,
                              hipStream_t stream) {
    const float* h   = (const float*)d_in[0];
    const int*   pid = (const int*)d_in[1];
    float*       out = (float*)d_out;
    (void)d_ws; (void)ws_size;

    topk_stream_kernel<<<dim3(BS * (NP / GRP)), dim3(128), 0, stream>>>(h, pid, out);
}